// Round 1
// baseline (57641.241 us; speedup 1.0000x reference)
//
#include <hip/hip_runtime.h>
#include <hip/hip_bf16.h>
#include <math.h>

#define T_ENC 2000
#define NB    128
#define LDEC  250
#define HDIM  512
#define KDIM  128
#define VDIM  128
#define ADIM  64
#define TC    100   // t-chunk for attention
#define NC    20    // number of chunks (TC*NC == T_ENC)

__device__ __forceinline__ float bf2f(unsigned int u) {
    return __uint_as_float(u << 16);
}

// ---------- one-time (per launch) prep kernels ----------

__global__ void cvt_bf16_kernel(const float* __restrict__ src,
                                unsigned short* __restrict__ dst, size_t n) {
    size_t i = (size_t)blockIdx.x * blockDim.x + threadIdx.x;
    size_t stride = (size_t)gridDim.x * blockDim.x;
    for (; i < n; i += stride) {
        unsigned int b = __float_as_uint(src[i]);
        unsigned int r = (b + 0x7fffu + ((b >> 16) & 1u)) >> 16;  // RNE
        dst[i] = (unsigned short)r;
    }
}

__global__ void transpose_kernel(const float* __restrict__ src,
                                 float* __restrict__ dst, int R, int C) {
    // dst[c*R + r] = src[r*C + c]
    int i = blockIdx.x * blockDim.x + threadIdx.x;
    int n = R * C;
    int stride = gridDim.x * blockDim.x;
    for (; i < n; i += stride) {
        int r = i / C, c = i - r * C;
        dst[c * R + r] = src[i];
    }
}

__global__ void init_state_kernel(float* h1, float* c1, float* h2, float* c2,
                                  float* ctx, const float* __restrict__ values) {
    int i = blockIdx.x * blockDim.x + threadIdx.x;
    int stride = gridDim.x * blockDim.x;
    for (int j = i; j < NB * HDIM; j += stride) { h1[j] = 0.f; c1[j] = 0.f; }
    for (int j = i; j < NB * KDIM; j += stride) {
        h2[j] = 0.f; c2[j] = 0.f;
        ctx[j] = values[j];   // values[0] slice: (N,V) contiguous at front
    }
}

// ---------- per-step kernels ----------

// grid (16 n-tiles, 16 col-tiles), block 256: thread = (n_local<3b>, jc<5b>)
__global__ __launch_bounds__(256) void lstm1_step(
    const int* __restrict__ text, const float* __restrict__ emb,
    const float* __restrict__ ctx, const float* __restrict__ h1_in,
    float* __restrict__ h1_out, float* __restrict__ c1,
    const float* __restrict__ WihT, const float* __restrict__ WhhT,
    const float* __restrict__ b_ih, const float* __restrict__ b_hh, int t)
{
    __shared__ float xa[8][HDIM + VDIM];  // [e | ctx]
    __shared__ float xh[8][HDIM];
    int n0 = blockIdx.x * 8;
    int j0 = blockIdx.y * 32;
    int tid = threadIdx.x;

    for (int nl = 0; nl < 8; ++nl) {
        int n = n0 + nl;
        int tok = text[n * LDEC + t];
        for (int i = tid; i < HDIM; i += 256)
            xa[nl][i] = tok ? emb[tok * HDIM + i] : 0.f;
        for (int i = tid; i < VDIM; i += 256)
            xa[nl][HDIM + i] = ctx[n * VDIM + i];
        for (int i = tid; i < HDIM; i += 256)
            xh[nl][i] = h1_in[n * HDIM + i];
    }
    __syncthreads();

    int nl = tid >> 5, jc = tid & 31;
    int j = j0 + jc;
    float acc0 = b_ih[0 * HDIM + j] + b_hh[0 * HDIM + j];
    float acc1 = b_ih[1 * HDIM + j] + b_hh[1 * HDIM + j];
    float acc2 = b_ih[2 * HDIM + j] + b_hh[2 * HDIM + j];
    float acc3 = b_ih[3 * HDIM + j] + b_hh[3 * HDIM + j];

    const float* w = WihT + j;  // WihT[i*2048 + g*512 + j]
#pragma unroll 4
    for (int i = 0; i < HDIM + VDIM; ++i) {
        float x = xa[nl][i];
        const float* wr = w + (size_t)i * 2048;
        acc0 += x * wr[0];
        acc1 += x * wr[512];
        acc2 += x * wr[1024];
        acc3 += x * wr[1536];
    }
    const float* w2 = WhhT + j;
#pragma unroll 4
    for (int i = 0; i < HDIM; ++i) {
        float x = xh[nl][i];
        const float* wr = w2 + (size_t)i * 2048;
        acc0 += x * wr[0];
        acc1 += x * wr[512];
        acc2 += x * wr[1024];
        acc3 += x * wr[1536];
    }
    int n = n0 + nl;
    float cc = c1[n * HDIM + j];
    float ig = 1.f / (1.f + expf(-acc0));
    float fg = 1.f / (1.f + expf(-acc1));
    float gg = tanhf(acc2);
    float og = 1.f / (1.f + expf(-acc3));
    float cn = fg * cc + ig * gg;
    c1[n * HDIM + j] = cn;
    h1_out[n * HDIM + j] = og * tanhf(cn);
}

// grid (16 n-tiles, 4 col-tiles), block 256
__global__ __launch_bounds__(256) void lstm2_step(
    const float* __restrict__ h1, const float* __restrict__ h2_in,
    float* __restrict__ h2_out, float* __restrict__ c2,
    const float* __restrict__ WihT2, const float* __restrict__ WhhT2,
    const float* __restrict__ b_ih, const float* __restrict__ b_hh)
{
    __shared__ float x1[8][HDIM];
    __shared__ float x2[8][KDIM];
    int n0 = blockIdx.x * 8;
    int j0 = blockIdx.y * 32;
    int tid = threadIdx.x;

    for (int nl = 0; nl < 8; ++nl) {
        int n = n0 + nl;
        for (int i = tid; i < HDIM; i += 256) x1[nl][i] = h1[n * HDIM + i];
        for (int i = tid; i < KDIM; i += 256) x2[nl][i] = h2_in[n * KDIM + i];
    }
    __syncthreads();

    int nl = tid >> 5, jc = tid & 31;
    int j = j0 + jc;
    float acc0 = b_ih[0 * KDIM + j] + b_hh[0 * KDIM + j];
    float acc1 = b_ih[1 * KDIM + j] + b_hh[1 * KDIM + j];
    float acc2 = b_ih[2 * KDIM + j] + b_hh[2 * KDIM + j];
    float acc3 = b_ih[3 * KDIM + j] + b_hh[3 * KDIM + j];

    const float* w = WihT2 + j;  // WihT2[i*512 + g*128 + j]
#pragma unroll 4
    for (int i = 0; i < HDIM; ++i) {
        float x = x1[nl][i];
        const float* wr = w + (size_t)i * 512;
        acc0 += x * wr[0];
        acc1 += x * wr[128];
        acc2 += x * wr[256];
        acc3 += x * wr[384];
    }
    const float* w2 = WhhT2 + j;
#pragma unroll 4
    for (int i = 0; i < KDIM; ++i) {
        float x = x2[nl][i];
        const float* wr = w2 + (size_t)i * 512;
        acc0 += x * wr[0];
        acc1 += x * wr[128];
        acc2 += x * wr[256];
        acc3 += x * wr[384];
    }
    int n = n0 + nl;
    float cc = c2[n * KDIM + j];
    float ig = 1.f / (1.f + expf(-acc0));
    float fg = 1.f / (1.f + expf(-acc1));
    float gg = tanhf(acc2);
    float og = 1.f / (1.f + expf(-acc3));
    float cn = fg * cc + ig * gg;
    c2[n * KDIM + j] = cn;
    h2_out[n * KDIM + j] = og * tanhf(cn);
}

// grid (NB, NC), block 256 (4 waves)
__global__ __launch_bounds__(256) void attn_partial(
    const unsigned short* __restrict__ kbf, const unsigned short* __restrict__ vbf,
    const float* __restrict__ h2, const int* __restrict__ lens,
    float* __restrict__ pmax, float* __restrict__ psum, float* __restrict__ pctx)
{
    int n = blockIdx.x;
    int c = blockIdx.y;
    int t0 = c * TC;
    int tid = threadIdx.x;
    int lane = tid & 63, w = tid >> 6;

    __shared__ float h2s[KDIM];
    __shared__ float pls[TC];
    __shared__ float red[8];
    __shared__ float cpart[4][VDIM];

    if (tid < KDIM) h2s[tid] = h2[n * KDIM + tid];
    int len = lens[n];
    __syncthreads();

    float h0 = h2s[2 * lane], h1v = h2s[2 * lane + 1];
    for (int tl = w; tl < TC; tl += 4) {
        int t = t0 + tl;
        float s;
        if (t < len) {
            unsigned int u = *(const unsigned int*)(kbf + ((size_t)t * NB + n) * KDIM + 2 * lane);
            s = bf2f(u & 0xffffu) * h0 + bf2f(u >> 16) * h1v;
            for (int k = 32; k >= 1; k >>= 1) s += __shfl_xor(s, k, 64);
        } else {
            s = -1e30f;
        }
        if (lane == 0) pls[tl] = s;
    }
    __syncthreads();

    // block max
    float m = -1e30f;
    for (int i = tid; i < TC; i += 256) m = fmaxf(m, pls[i]);
    for (int k = 32; k >= 1; k >>= 1) m = fmaxf(m, __shfl_xor(m, k, 64));
    if (lane == 0) red[w] = m;
    __syncthreads();
    m = fmaxf(fmaxf(red[0], red[1]), fmaxf(red[2], red[3]));
    bool empty = (m <= -1e29f);

    float ssum = 0.f;
    for (int i = tid; i < TC; i += 256) {
        float pv = empty ? 0.f : expf(pls[i] - m);
        pls[i] = pv;
        ssum += pv;
    }
    __syncthreads();  // pls rewritten; make visible before phase 3
    for (int k = 32; k >= 1; k >>= 1) ssum += __shfl_xor(ssum, k, 64);
    if (lane == 0) red[4 + w] = ssum;
    __syncthreads();
    if (tid == 0) {
        pmax[n * NC + c] = empty ? -1e30f : m;
        psum[n * NC + c] = red[4] + red[5] + red[6] + red[7];
    }

    // ctx partial: wave w handles tl in [w*25, (w+1)*25)
    float a0 = 0.f, a1 = 0.f;
    for (int tl = w * 25; tl < (w + 1) * 25; ++tl) {
        int t = t0 + tl;
        float pv = pls[tl];
        unsigned int u = *(const unsigned int*)(vbf + ((size_t)t * NB + n) * VDIM + 2 * lane);
        a0 += pv * bf2f(u & 0xffffu);
        a1 += pv * bf2f(u >> 16);
    }
    cpart[w][2 * lane] = a0;
    cpart[w][2 * lane + 1] = a1;
    __syncthreads();
    if (tid < VDIM) {
        pctx[((size_t)n * NC + c) * VDIM + tid] =
            cpart[0][tid] + cpart[1][tid] + cpart[2][tid] + cpart[3][tid];
    }
}

// grid NB, block 64 (1 wave)
__global__ __launch_bounds__(64) void combine_pred(
    const float* __restrict__ pmax, const float* __restrict__ psum,
    const float* __restrict__ pctx, const float* __restrict__ h2,
    float* __restrict__ ctx, const float* __restrict__ W_mos,
    const float* __restrict__ b_mos, float* __restrict__ out, int t)
{
    int n = blockIdx.x;
    int lane = threadIdx.x;

    float m = (lane < NC) ? pmax[n * NC + lane] : -1e30f;
    for (int k = 32; k >= 1; k >>= 1) m = fmaxf(m, __shfl_xor(m, k, 64));
    float s = (lane < NC) ? psum[n * NC + lane] * expf(pmax[n * NC + lane] - m) : 0.f;
    for (int k = 32; k >= 1; k >>= 1) s += __shfl_xor(s, k, 64);
    float inv = 1.f / s;

    __shared__ float xcat[2 * KDIM];
#pragma unroll
    for (int v2 = 0; v2 < 2; ++v2) {
        int v = lane + v2 * 64;
        float acc = 0.f;
        for (int c = 0; c < NC; ++c) {
            float e = expf(pmax[n * NC + c] - m);
            acc += pctx[((size_t)n * NC + c) * VDIM + v] * e;
        }
        acc *= inv;
        ctx[n * VDIM + v] = acc;
        xcat[KDIM + v] = acc;
    }
    xcat[lane] = h2[n * KDIM + lane];
    xcat[64 + lane] = h2[n * KDIM + 64 + lane];
    __syncthreads();

    float acc = b_mos[lane];
    const float* wr = W_mos + lane * (2 * KDIM);
#pragma unroll 4
    for (int i = 0; i < 2 * KDIM; ++i) acc += xcat[i] * wr[i];
    out[((size_t)n * LDEC + t) * ADIM + lane] = acc;
}

// ---------- launcher ----------

extern "C" void kernel_launch(void* const* d_in, const int* in_sizes, int n_in,
                              void* d_out, int out_size, void* d_ws, size_t ws_size,
                              hipStream_t stream)
{
    const float* key    = (const float*)d_in[0];
    const float* values = (const float*)d_in[1];
    const int*   lens   = (const int*)d_in[2];
    const int*   text   = (const int*)d_in[3];
    const float* emb    = (const float*)d_in[4];
    const float* W_ih1  = (const float*)d_in[5];
    const float* W_hh1  = (const float*)d_in[6];
    const float* b_ih1  = (const float*)d_in[7];
    const float* b_hh1  = (const float*)d_in[8];
    const float* W_ih2  = (const float*)d_in[9];
    const float* W_hh2  = (const float*)d_in[10];
    const float* b_ih2  = (const float*)d_in[11];
    const float* b_hh2  = (const float*)d_in[12];
    const float* W_mos  = (const float*)d_in[13];
    const float* b_mos  = (const float*)d_in[14];
    float* out = (float*)d_out;

    char* base = (char*)d_ws;
    size_t off = 0;
    auto alloc = [&](size_t bytes) -> char* {
        char* r = base + off;
        off += (bytes + 255) & ~(size_t)255;
        return r;
    };
    unsigned short* kbf = (unsigned short*)alloc((size_t)T_ENC * NB * KDIM * 2);
    unsigned short* vbf = (unsigned short*)alloc((size_t)T_ENC * NB * VDIM * 2);
    float* WihT1 = (float*)alloc((size_t)(HDIM + VDIM) * 4 * HDIM * 4);
    float* WhhT1 = (float*)alloc((size_t)HDIM * 4 * HDIM * 4);
    float* WihT2 = (float*)alloc((size_t)HDIM * 4 * KDIM * 4);
    float* WhhT2 = (float*)alloc((size_t)KDIM * 4 * KDIM * 4);
    float* h1a = (float*)alloc((size_t)NB * HDIM * 4);
    float* h1b = (float*)alloc((size_t)NB * HDIM * 4);
    float* c1  = (float*)alloc((size_t)NB * HDIM * 4);
    float* h2a = (float*)alloc((size_t)NB * KDIM * 4);
    float* h2b = (float*)alloc((size_t)NB * KDIM * 4);
    float* c2  = (float*)alloc((size_t)NB * KDIM * 4);
    float* ctx = (float*)alloc((size_t)NB * VDIM * 4);
    float* pmax = (float*)alloc((size_t)NB * NC * 4);
    float* psum = (float*)alloc((size_t)NB * NC * 4);
    float* pctx = (float*)alloc((size_t)NB * NC * VDIM * 4);
    (void)ws_size; (void)in_sizes; (void)n_in; (void)out_size;

    cvt_bf16_kernel<<<2048, 256, 0, stream>>>(key, kbf, (size_t)T_ENC * NB * KDIM);
    cvt_bf16_kernel<<<2048, 256, 0, stream>>>(values, vbf, (size_t)T_ENC * NB * VDIM);
    transpose_kernel<<<1024, 256, 0, stream>>>(W_ih1, WihT1, 4 * HDIM, HDIM + VDIM);
    transpose_kernel<<<1024, 256, 0, stream>>>(W_hh1, WhhT1, 4 * HDIM, HDIM);
    transpose_kernel<<<512, 256, 0, stream>>>(W_ih2, WihT2, 4 * KDIM, HDIM);
    transpose_kernel<<<256, 256, 0, stream>>>(W_hh2, WhhT2, 4 * KDIM, KDIM);
    init_state_kernel<<<256, 256, 0, stream>>>(h1a, c1, h2a, c2, ctx, values);

    for (int t = 0; t < LDEC; ++t) {
        float* h1i = (t & 1) ? h1b : h1a;
        float* h1o = (t & 1) ? h1a : h1b;
        float* h2i = (t & 1) ? h2b : h2a;
        float* h2o = (t & 1) ? h2a : h2b;
        lstm1_step<<<dim3(16, 16), 256, 0, stream>>>(text, emb, ctx, h1i, h1o, c1,
                                                     WihT1, WhhT1, b_ih1, b_hh1, t);
        lstm2_step<<<dim3(16, 4), 256, 0, stream>>>(h1o, h2i, h2o, c2,
                                                    WihT2, WhhT2, b_ih2, b_hh2);
        attn_partial<<<dim3(NB, NC), 256, 0, stream>>>(kbf, vbf, h2o, lens,
                                                       pmax, psum, pctx);
        combine_pred<<<NB, 64, 0, stream>>>(pmax, psum, pctx, h2o, ctx,
                                            W_mos, b_mos, out, t);
    }
}

// Round 3
// 18595.871 us; speedup vs baseline: 3.0997x; 3.0997x over previous
//
#include <hip/hip_runtime.h>
#include <hip/hip_bf16.h>
#include <math.h>

#define T_ENC 2000
#define NB    128
#define LDEC  250
#define HDIM  512
#define KDIM  128
#define VDIM  128
#define ADIM  64
#define TC    100
#define NC    20
#define K1    1152   // 512 emb + 128 ctx + 512 h1
#define K2    640    // 512 h1 + 128 h2
#define N1    2048
#define N2    512

typedef __attribute__((ext_vector_type(8))) short bf16x8;
typedef __attribute__((ext_vector_type(4))) float f32x4;
typedef unsigned short u16;

__device__ __forceinline__ u16 f2bf(float x) {
    unsigned int b = __float_as_uint(x);
    b += 0x7fffu + ((b >> 16) & 1u);
    return (u16)(b >> 16);
}
__device__ __forceinline__ float bfhi2f(unsigned int u) {
    return __uint_as_float(u << 16);
}
__device__ __forceinline__ f32x4 mfma16(bf16x8 a, bf16x8 b, f32x4 c) {
    return __builtin_amdgcn_mfma_f32_16x16x32_bf16(a, b, c, 0, 0, 0);
}

// ---------------- one-time prep ----------------

// src (T,N,128) f32 -> dst (N,T,128) bf16
__global__ void cvt_tr(const float* __restrict__ src, u16* __restrict__ dst) {
    size_t total = (size_t)T_ENC * NB * 128;
    for (size_t idx = (size_t)blockIdx.x * 256 + threadIdx.x; idx < total;
         idx += (size_t)gridDim.x * 256) {
        int t = idx >> 14;            // 128*128 = 16384
        int n = (idx >> 7) & 127;
        int d = idx & 127;
        dst[((size_t)n * T_ENC + t) * 128 + d] = f2bf(src[idx]);
    }
}

// E (t,n,d) bf16 hi/lo from emb[text], padding_idx=0
__global__ void prep_emb(const int* __restrict__ text, const float* __restrict__ emb,
                         u16* __restrict__ Ehi, u16* __restrict__ Elo) {
    size_t total = (size_t)LDEC * NB * HDIM;
    for (size_t idx = (size_t)blockIdx.x * 256 + threadIdx.x; idx < total;
         idx += (size_t)gridDim.x * 256) {
        int t = idx >> 16;            // 128*512 = 65536
        int n = (idx >> 9) & 127;
        int d = idx & 511;
        int tok = text[n * LDEC + t];
        float v = tok ? emb[(size_t)tok * HDIM + d] : 0.f;
        u16 hi = f2bf(v);
        Ehi[idx] = hi;
        Elo[idx] = f2bf(v - bfhi2f((unsigned int)hi));
    }
}

__global__ void prep_w1(const float* __restrict__ Wih, const float* __restrict__ Whh,
                        const float* __restrict__ bi, const float* __restrict__ bh,
                        u16* __restrict__ Whi, u16* __restrict__ Wlo,
                        float* __restrict__ bsum) {
    size_t total = (size_t)N1 * K1;
    for (size_t idx = (size_t)blockIdx.x * 256 + threadIdx.x; idx < total;
         idx += (size_t)gridDim.x * 256) {
        int c = idx / K1, k = idx % K1;
        float w = (k < 640) ? Wih[(size_t)c * 640 + k] : Whh[(size_t)c * 512 + (k - 640)];
        u16 hi = f2bf(w);
        Whi[idx] = hi;
        Wlo[idx] = f2bf(w - bfhi2f((unsigned int)hi));
    }
    int i = blockIdx.x * 256 + threadIdx.x;
    if (i < N1) bsum[i] = bi[i] + bh[i];
}

__global__ void prep_w2(const float* __restrict__ Wih, const float* __restrict__ Whh,
                        const float* __restrict__ bi, const float* __restrict__ bh,
                        u16* __restrict__ Whi, u16* __restrict__ Wlo,
                        float* __restrict__ bsum) {
    size_t total = (size_t)N2 * K2;
    for (size_t idx = (size_t)blockIdx.x * 256 + threadIdx.x; idx < total;
         idx += (size_t)gridDim.x * 256) {
        int c = idx / K2, k = idx % K2;
        float w = (k < 512) ? Wih[(size_t)c * 512 + k] : Whh[(size_t)c * 128 + (k - 512)];
        u16 hi = f2bf(w);
        Whi[idx] = hi;
        Wlo[idx] = f2bf(w - bfhi2f((unsigned int)hi));
    }
    int i = blockIdx.x * 256 + threadIdx.x;
    if (i < N2) bsum[i] = bi[i] + bh[i];
}

__global__ void init_state(float* c1, u16* h1hi, u16* h1lo,
                           float* c2, u16* h2hi, u16* h2lo,
                           u16* cxhi, u16* cxlo, const float* __restrict__ values) {
    int i = blockIdx.x * 256 + threadIdx.x;   // grid 256 -> 65536 threads
    c1[i] = 0.f; h1hi[i] = 0; h1lo[i] = 0;
    if (i < NB * KDIM) {
        c2[i] = 0.f; h2hi[i] = 0; h2lo[i] = 0;
        float v = values[i];                  // values[0] slice (N,V)
        u16 hi = f2bf(v);
        cxhi[i] = hi; cxlo[i] = f2bf(v - bfhi2f((unsigned int)hi));
    }
}

// ---------------- per-step kernels ----------------

// grid (2 n-tiles, 16 j-tiles, 4 k-chunks), block 256 = 4 waves (2 wn x 2 wj)
// wave tile: 32 n x (16 j x 4 gates); writes f32 partials gpart[ks][n][2048]
__global__ __launch_bounds__(256) void lstm1_mfma(
    const u16* __restrict__ Ehi, const u16* __restrict__ Elo,
    const u16* __restrict__ cxhi, const u16* __restrict__ cxlo,
    const u16* __restrict__ h1hi, const u16* __restrict__ h1lo,
    const u16* __restrict__ W1hi, const u16* __restrict__ W1lo,
    float* __restrict__ gpart, int t)
{
    int tid = threadIdx.x, lane = tid & 63, wid = tid >> 6;
    int wn = wid >> 1, wj = wid & 1;
    int l15 = lane & 15, l4 = lane >> 4;
    int n0 = blockIdx.x * 64 + wn * 32;
    int j0 = blockIdx.y * 32 + wj * 16;
    int ks = blockIdx.z;
    int kbeg = ks * 288, kend = kbeg + 288;

    f32x4 zero = {0.f, 0.f, 0.f, 0.f};
    f32x4 acc[2][4];
#pragma unroll
    for (int m = 0; m < 2; ++m)
#pragma unroll
        for (int g = 0; g < 4; ++g) acc[m][g] = zero;

    size_t brow[4];
#pragma unroll
    for (int g = 0; g < 4; ++g) brow[g] = (size_t)(g * 512 + j0 + l15) * K1;
    int row0 = n0 + l15, row1 = n0 + 16 + l15;
    const u16* Et_hi = Ehi + (size_t)t * (NB * HDIM);
    const u16* Et_lo = Elo + (size_t)t * (NB * HDIM);

    for (int kk = kbeg; kk < kend; kk += 32) {
        int kb = kk + l4 * 8;
        const u16 *pah, *pal; size_t ao0, ao1;
        if (kk < 512) {
            pah = Et_hi; pal = Et_lo;
            ao0 = (size_t)row0 * 512 + kb; ao1 = (size_t)row1 * 512 + kb;
        } else if (kk < 640) {
            pah = cxhi; pal = cxlo;
            ao0 = (size_t)row0 * 128 + (kb - 512); ao1 = (size_t)row1 * 128 + (kb - 512);
        } else {
            pah = h1hi; pal = h1lo;
            ao0 = (size_t)row0 * 512 + (kb - 640); ao1 = (size_t)row1 * 512 + (kb - 640);
        }
        bf16x8 a0h = *(const bf16x8*)(pah + ao0);
        bf16x8 a0l = *(const bf16x8*)(pal + ao0);
        bf16x8 a1h = *(const bf16x8*)(pah + ao1);
        bf16x8 a1l = *(const bf16x8*)(pal + ao1);
#pragma unroll
        for (int g = 0; g < 4; ++g) {
            bf16x8 bh = *(const bf16x8*)(W1hi + brow[g] + kb);
            bf16x8 bl = *(const bf16x8*)(W1lo + brow[g] + kb);
            acc[0][g] = mfma16(a0h, bh, acc[0][g]);
            acc[0][g] = mfma16(a0h, bl, acc[0][g]);
            acc[0][g] = mfma16(a0l, bh, acc[0][g]);
            acc[1][g] = mfma16(a1h, bh, acc[1][g]);
            acc[1][g] = mfma16(a1h, bl, acc[1][g]);
            acc[1][g] = mfma16(a1l, bh, acc[1][g]);
        }
    }
#pragma unroll
    for (int mi = 0; mi < 2; ++mi)
#pragma unroll
        for (int g = 0; g < 4; ++g)
#pragma unroll
            for (int r = 0; r < 4; ++r) {
                int row = n0 + mi * 16 + l4 * 4 + r;
                gpart[((size_t)ks * NB + row) * N1 + g * 512 + j0 + l15] = acc[mi][g][r];
            }
}

// 65536 threads: gates -> c1, h1 (bf16 hi/lo)
__global__ __launch_bounds__(256) void pw1(
    const float* __restrict__ gpart, const float* __restrict__ bsum,
    float* __restrict__ c1, u16* __restrict__ h1hi, u16* __restrict__ h1lo)
{
    int idx = blockIdx.x * 256 + threadIdx.x;   // n*512 + j
    int n = idx >> 9, j = idx & 511;
    float g[4];
#pragma unroll
    for (int gi = 0; gi < 4; ++gi) {
        int c = gi * 512 + j;
        float s = bsum[c];
#pragma unroll
        for (int ks = 0; ks < 4; ++ks) s += gpart[((size_t)ks * NB + n) * N1 + c];
        g[gi] = s;
    }
    float cc = c1[idx];
    float i_ = 1.f / (1.f + expf(-g[0]));
    float f_ = 1.f / (1.f + expf(-g[1]));
    float g_ = tanhf(g[2]);
    float o_ = 1.f / (1.f + expf(-g[3]));
    float cn = f_ * cc + i_ * g_;
    c1[idx] = cn;
    float h = o_ * tanhf(cn);
    u16 hi = f2bf(h);
    h1hi[idx] = hi;
    h1lo[idx] = f2bf(h - bfhi2f((unsigned int)hi));
}

// grid (2 n-tiles, 4 j-tiles, 4 k-chunks), block 256
__global__ __launch_bounds__(256) void lstm2_mfma(
    const u16* __restrict__ h1hi, const u16* __restrict__ h1lo,
    const u16* __restrict__ h2hi, const u16* __restrict__ h2lo,
    const u16* __restrict__ W2hi, const u16* __restrict__ W2lo,
    float* __restrict__ gpart)
{
    int tid = threadIdx.x, lane = tid & 63, wid = tid >> 6;
    int wn = wid >> 1, wj = wid & 1;
    int l15 = lane & 15, l4 = lane >> 4;
    int n0 = blockIdx.x * 64 + wn * 32;
    int j0 = blockIdx.y * 32 + wj * 16;   // j in [0,128)
    int ks = blockIdx.z;
    int kbeg = ks * 160, kend = kbeg + 160;

    f32x4 zero = {0.f, 0.f, 0.f, 0.f};
    f32x4 acc[2][4];
#pragma unroll
    for (int m = 0; m < 2; ++m)
#pragma unroll
        for (int g = 0; g < 4; ++g) acc[m][g] = zero;

    size_t brow[4];
#pragma unroll
    for (int g = 0; g < 4; ++g) brow[g] = (size_t)(g * 128 + j0 + l15) * K2;
    int row0 = n0 + l15, row1 = n0 + 16 + l15;

    for (int kk = kbeg; kk < kend; kk += 32) {
        int kb = kk + l4 * 8;
        const u16 *pah, *pal; size_t ao0, ao1;
        if (kk < 512) {
            pah = h1hi; pal = h1lo;
            ao0 = (size_t)row0 * 512 + kb; ao1 = (size_t)row1 * 512 + kb;
        } else {
            pah = h2hi; pal = h2lo;
            ao0 = (size_t)row0 * 128 + (kb - 512); ao1 = (size_t)row1 * 128 + (kb - 512);
        }
        bf16x8 a0h = *(const bf16x8*)(pah + ao0);
        bf16x8 a0l = *(const bf16x8*)(pal + ao0);
        bf16x8 a1h = *(const bf16x8*)(pah + ao1);
        bf16x8 a1l = *(const bf16x8*)(pal + ao1);
#pragma unroll
        for (int g = 0; g < 4; ++g) {
            bf16x8 bh = *(const bf16x8*)(W2hi + brow[g] + kb);
            bf16x8 bl = *(const bf16x8*)(W2lo + brow[g] + kb);
            acc[0][g] = mfma16(a0h, bh, acc[0][g]);
            acc[0][g] = mfma16(a0h, bl, acc[0][g]);
            acc[0][g] = mfma16(a0l, bh, acc[0][g]);
            acc[1][g] = mfma16(a1h, bh, acc[1][g]);
            acc[1][g] = mfma16(a1h, bl, acc[1][g]);
            acc[1][g] = mfma16(a1l, bh, acc[1][g]);
        }
    }
#pragma unroll
    for (int mi = 0; mi < 2; ++mi)
#pragma unroll
        for (int g = 0; g < 4; ++g)
#pragma unroll
            for (int r = 0; r < 4; ++r) {
                int row = n0 + mi * 16 + l4 * 4 + r;
                gpart[((size_t)ks * NB + row) * N2 + g * 128 + j0 + l15] = acc[mi][g][r];
            }
}

// 16384 threads: gates2 -> c2, h2f, h2 (bf16 hi/lo)
__global__ __launch_bounds__(256) void pw2(
    const float* __restrict__ gpart, const float* __restrict__ bsum,
    float* __restrict__ c2, float* __restrict__ h2f,
    u16* __restrict__ h2hi, u16* __restrict__ h2lo)
{
    int idx = blockIdx.x * 256 + threadIdx.x;   // n*128 + j
    int n = idx >> 7, j = idx & 127;
    float g[4];
#pragma unroll
    for (int gi = 0; gi < 4; ++gi) {
        int c = gi * 128 + j;
        float s = bsum[c];
#pragma unroll
        for (int ks = 0; ks < 4; ++ks) s += gpart[((size_t)ks * NB + n) * N2 + c];
        g[gi] = s;
    }
    float cc = c2[idx];
    float i_ = 1.f / (1.f + expf(-g[0]));
    float f_ = 1.f / (1.f + expf(-g[1]));
    float g_ = tanhf(g[2]);
    float o_ = 1.f / (1.f + expf(-g[3]));
    float cn = f_ * cc + i_ * g_;
    c2[idx] = cn;
    float h = o_ * tanhf(cn);
    h2f[idx] = h;
    u16 hi = f2bf(h);
    h2hi[idx] = hi;
    h2lo[idx] = f2bf(h - bfhi2f((unsigned int)hi));
}

// grid (NB, NC), block 256 (4 waves). kbf/vbf are (n, t, 128) bf16.
__global__ __launch_bounds__(256) void attn_partial(
    const u16* __restrict__ kbf, const u16* __restrict__ vbf,
    const float* __restrict__ h2f, const int* __restrict__ lens,
    float* __restrict__ pmax, float* __restrict__ psum, float* __restrict__ pctx)
{
    int n = blockIdx.x, c = blockIdx.y, t0 = c * TC;
    int tid = threadIdx.x, lane = tid & 63, w = tid >> 6;
    int l15 = lane & 15, l4 = lane >> 4;
    __shared__ float pls[TC];
    __shared__ float red[8];
    __shared__ float cpart[4][VDIM];
    int len = lens[n];

    float h2r[8];
    {
        const float* hp = h2f + n * 128 + l15 * 8;
#pragma unroll
        for (int j = 0; j < 8; ++j) h2r[j] = hp[j];
    }

    const u16* kb_ = kbf + (size_t)n * T_ENC * 128;
    for (int q = w; q < 25; q += 4) {
        int tl = 4 * q + l4;
        int t = t0 + tl;
        uint4 u = *(const uint4*)(kb_ + (size_t)t * 128 + l15 * 8);
        float s = 0.f;
        s = fmaf(bfhi2f(u.x & 0xffffu), h2r[0], s);
        s = fmaf(bfhi2f(u.x >> 16),     h2r[1], s);
        s = fmaf(bfhi2f(u.y & 0xffffu), h2r[2], s);
        s = fmaf(bfhi2f(u.y >> 16),     h2r[3], s);
        s = fmaf(bfhi2f(u.z & 0xffffu), h2r[4], s);
        s = fmaf(bfhi2f(u.z >> 16),     h2r[5], s);
        s = fmaf(bfhi2f(u.w & 0xffffu), h2r[6], s);
        s = fmaf(bfhi2f(u.w >> 16),     h2r[7], s);
        s += __shfl_xor(s, 1, 64);
        s += __shfl_xor(s, 2, 64);
        s += __shfl_xor(s, 4, 64);
        s += __shfl_xor(s, 8, 64);
        if (t >= len) s = -1e30f;
        if (l15 == 0) pls[tl] = s;
    }
    __syncthreads();

    float m = -1e30f;
    for (int i = tid; i < TC; i += 256) m = fmaxf(m, pls[i]);
    for (int k = 32; k >= 1; k >>= 1) m = fmaxf(m, __shfl_xor(m, k, 64));
    if (lane == 0) red[w] = m;
    __syncthreads();
    m = fmaxf(fmaxf(red[0], red[1]), fmaxf(red[2], red[3]));
    bool empty = (m <= -1e29f);

    float ssum = 0.f;
    for (int i = tid; i < TC; i += 256) {
        float pv = empty ? 0.f : expf(pls[i] - m);
        pls[i] = pv;
        ssum += pv;
    }
    __syncthreads();
    for (int k = 32; k >= 1; k >>= 1) ssum += __shfl_xor(ssum, k, 64);
    if (lane == 0) red[4 + w] = ssum;
    __syncthreads();
    if (tid == 0) {
        pmax[n * NC + c] = empty ? -1e30f : m;
        psum[n * NC + c] = red[4] + red[5] + red[6] + red[7];
    }

    const u16* vb_ = vbf + (size_t)n * T_ENC * 128;
    int l5 = lane >> 5, l31 = lane & 31;
    float a4[4] = {0.f, 0.f, 0.f, 0.f};
    for (int p = w; p < 50; p += 4) {
        int tl = 2 * p + l5;
        int t = t0 + tl;
        float pv = pls[tl];
        uint2 u = *(const uint2*)(vb_ + (size_t)t * 128 + l31 * 4);
        a4[0] = fmaf(pv, bfhi2f(u.x & 0xffffu), a4[0]);
        a4[1] = fmaf(pv, bfhi2f(u.x >> 16),     a4[1]);
        a4[2] = fmaf(pv, bfhi2f(u.y & 0xffffu), a4[2]);
        a4[3] = fmaf(pv, bfhi2f(u.y >> 16),     a4[3]);
    }
#pragma unroll
    for (int j = 0; j < 4; ++j) a4[j] += __shfl_xor(a4[j], 32, 64);
    if (lane < 32) {
#pragma unroll
        for (int j = 0; j < 4; ++j) cpart[w][l31 * 4 + j] = a4[j];
    }
    __syncthreads();
    if (tid < 128)
        pctx[((size_t)n * NC + c) * VDIM + tid] =
            cpart[0][tid] + cpart[1][tid] + cpart[2][tid] + cpart[3][tid];
}

// grid NB, block 64
__global__ __launch_bounds__(64) void combine_pred(
    const float* __restrict__ pmax, const float* __restrict__ psum,
    const float* __restrict__ pctx, const float* __restrict__ h2f,
    u16* __restrict__ cxhi, u16* __restrict__ cxlo,
    const float* __restrict__ W_mos, const float* __restrict__ b_mos,
    float* __restrict__ out, int t)
{
    int n = blockIdx.x;
    int lane = threadIdx.x;

    float m = (lane < NC) ? pmax[n * NC + lane] : -1e30f;
    for (int k = 32; k >= 1; k >>= 1) m = fmaxf(m, __shfl_xor(m, k, 64));
    float s = (lane < NC) ? psum[n * NC + lane] * expf(pmax[n * NC + lane] - m) : 0.f;
    for (int k = 32; k >= 1; k >>= 1) s += __shfl_xor(s, k, 64);
    float inv = 1.f / s;

    __shared__ float xcat[2 * KDIM];
#pragma unroll
    for (int v2 = 0; v2 < 2; ++v2) {
        int v = lane + v2 * 64;
        float acc = 0.f;
        for (int c = 0; c < NC; ++c) {
            float e = expf(pmax[n * NC + c] - m);
            acc += pctx[((size_t)n * NC + c) * VDIM + v] * e;
        }
        acc *= inv;
        u16 hi = f2bf(acc);
        cxhi[n * 128 + v] = hi;
        cxlo[n * 128 + v] = f2bf(acc - bfhi2f((unsigned int)hi));
        xcat[KDIM + v] = acc;
    }
    xcat[lane] = h2f[n * 128 + lane];
    xcat[64 + lane] = h2f[n * 128 + 64 + lane];
    __syncthreads();

    float acc = b_mos[lane];
    const float* wr = W_mos + lane * (2 * KDIM);
#pragma unroll 4
    for (int i = 0; i < 2 * KDIM; ++i) acc += xcat[i] * wr[i];
    out[((size_t)n * LDEC + t) * ADIM + lane] = acc;
}

// ---------------- launcher ----------------

extern "C" void kernel_launch(void* const* d_in, const int* in_sizes, int n_in,
                              void* d_out, int out_size, void* d_ws, size_t ws_size,
                              hipStream_t stream)
{
    const float* key    = (const float*)d_in[0];
    const float* values = (const float*)d_in[1];
    const int*   lens   = (const int*)d_in[2];
    const int*   text   = (const int*)d_in[3];
    const float* emb    = (const float*)d_in[4];
    const float* W_ih1  = (const float*)d_in[5];
    const float* W_hh1  = (const float*)d_in[6];
    const float* b_ih1  = (const float*)d_in[7];
    const float* b_hh1  = (const float*)d_in[8];
    const float* W_ih2  = (const float*)d_in[9];
    const float* W_hh2  = (const float*)d_in[10];
    const float* b_ih2  = (const float*)d_in[11];
    const float* b_hh2  = (const float*)d_in[12];
    const float* W_mos  = (const float*)d_in[13];
    const float* b_mos  = (const float*)d_in[14];
    float* out = (float*)d_out;

    char* base = (char*)d_ws;
    size_t off = 0;
    auto alloc = [&](size_t bytes) -> char* {
        char* r = base + off;
        off += (bytes + 255) & ~(size_t)255;
        return r;
    };
    u16* kbf  = (u16*)alloc((size_t)T_ENC * NB * 128 * 2);
    u16* vbf  = (u16*)alloc((size_t)T_ENC * NB * 128 * 2);
    u16* Ehi  = (u16*)alloc((size_t)LDEC * NB * HDIM * 2);
    u16* Elo  = (u16*)alloc((size_t)LDEC * NB * HDIM * 2);
    u16* W1hi = (u16*)alloc((size_t)N1 * K1 * 2);
    u16* W1lo = (u16*)alloc((size_t)N1 * K1 * 2);
    u16* W2hi = (u16*)alloc((size_t)N2 * K2 * 2);
    u16* W2lo = (u16*)alloc((size_t)N2 * K2 * 2);
    float* bsum1 = (float*)alloc(N1 * 4);
    float* bsum2 = (float*)alloc(N2 * 4);
    float* gpart1 = (float*)alloc((size_t)4 * NB * N1 * 4);
    float* gpart2 = (float*)alloc((size_t)4 * NB * N2 * 4);
    u16* h1hiA = (u16*)alloc(NB * HDIM * 2);
    u16* h1loA = (u16*)alloc(NB * HDIM * 2);
    u16* h1hiB = (u16*)alloc(NB * HDIM * 2);
    u16* h1loB = (u16*)alloc(NB * HDIM * 2);
    u16* h2hiA = (u16*)alloc(NB * KDIM * 2);
    u16* h2loA = (u16*)alloc(NB * KDIM * 2);
    u16* h2hiB = (u16*)alloc(NB * KDIM * 2);
    u16* h2loB = (u16*)alloc(NB * KDIM * 2);
    float* c1  = (float*)alloc(NB * HDIM * 4);
    float* c2  = (float*)alloc(NB * KDIM * 4);
    float* h2f = (float*)alloc(NB * KDIM * 4);
    u16* cxhi = (u16*)alloc(NB * VDIM * 2);
    u16* cxlo = (u16*)alloc(NB * VDIM * 2);
    float* pmax = (float*)alloc(NB * NC * 4);
    float* psum = (float*)alloc(NB * NC * 4);
    float* pctx = (float*)alloc((size_t)NB * NC * VDIM * 4);
    (void)ws_size; (void)in_sizes; (void)n_in; (void)out_size;

    cvt_tr<<<4096, 256, 0, stream>>>(key, kbf);
    cvt_tr<<<4096, 256, 0, stream>>>(values, vbf);
    prep_emb<<<4096, 256, 0, stream>>>(text, emb, Ehi, Elo);
    prep_w1<<<2048, 256, 0, stream>>>(W_ih1, W_hh1, b_ih1, b_hh1, W1hi, W1lo, bsum1);
    prep_w2<<<512, 256, 0, stream>>>(W_ih2, W_hh2, b_ih2, b_hh2, W2hi, W2lo, bsum2);
    init_state<<<256, 256, 0, stream>>>(c1, h1hiA, h1loA, c2, h2hiA, h2loA,
                                        cxhi, cxlo, values);

    for (int t = 0; t < LDEC; ++t) {
        u16* h1hi_i = (t & 1) ? h1hiB : h1hiA;
        u16* h1lo_i = (t & 1) ? h1loB : h1loA;
        u16* h1hi_o = (t & 1) ? h1hiA : h1hiB;
        u16* h1lo_o = (t & 1) ? h1loA : h1loB;
        u16* h2hi_i = (t & 1) ? h2hiB : h2hiA;
        u16* h2lo_i = (t & 1) ? h2loB : h2loA;
        u16* h2hi_o = (t & 1) ? h2hiA : h2hiB;
        u16* h2lo_o = (t & 1) ? h2loA : h2loB;

        lstm1_mfma<<<dim3(2, 16, 4), 256, 0, stream>>>(
            Ehi, Elo, cxhi, cxlo, h1hi_i, h1lo_i, W1hi, W1lo, gpart1, t);
        pw1<<<256, 256, 0, stream>>>(gpart1, bsum1, c1, h1hi_o, h1lo_o);
        lstm2_mfma<<<dim3(2, 4, 4), 256, 0, stream>>>(
            h1hi_o, h1lo_o, h2hi_i, h2lo_i, W2hi, W2lo, gpart2);
        pw2<<<64, 256, 0, stream>>>(gpart2, bsum2, c2, h2f, h2hi_o, h2lo_o);
        attn_partial<<<dim3(NB, NC), 256, 0, stream>>>(kbf, vbf, h2f, lens,
                                                       pmax, psum, pctx);
        combine_pred<<<NB, 64, 0, stream>>>(pmax, psum, pctx, h2f,
                                            cxhi, cxlo, W_mos, b_mos, out, t);
    }
}

// Round 4
// 15760.083 us; speedup vs baseline: 3.6574x; 1.1799x over previous
//
#include <hip/hip_runtime.h>
#include <hip/hip_bf16.h>
#include <math.h>

#define T_ENC 2000
#define NB    128
#define LDEC  250
#define HDIM  512
#define KDIM  128
#define VDIM  128
#define ADIM  64
#define TC    100
#define NC    20
#define K1    1152   // 512 emb + 128 ctx + 512 h1
#define K2    640    // 512 h1 + 128 h2
#define N1    2048
#define N2    512

typedef __attribute__((ext_vector_type(8))) short bf16x8;
typedef __attribute__((ext_vector_type(4))) float f32x4;
typedef unsigned short u16;

__device__ __forceinline__ u16 f2bf(float x) {
    unsigned int b = __float_as_uint(x);
    b += 0x7fffu + ((b >> 16) & 1u);
    return (u16)(b >> 16);
}
__device__ __forceinline__ float bfhi2f(unsigned int u) {
    return __uint_as_float(u << 16);
}
__device__ __forceinline__ f32x4 mfma16(bf16x8 a, bf16x8 b, f32x4 c) {
    return __builtin_amdgcn_mfma_f32_16x16x32_bf16(a, b, c, 0, 0, 0);
}

// ---------------- one-time prep ----------------

// src (T,N,128) f32 -> dst (N,T,128) bf16
__global__ void cvt_tr(const float* __restrict__ src, u16* __restrict__ dst) {
    size_t total = (size_t)T_ENC * NB * 128;
    for (size_t idx = (size_t)blockIdx.x * 256 + threadIdx.x; idx < total;
         idx += (size_t)gridDim.x * 256) {
        int t = idx >> 14;            // 128*128 = 16384
        int n = (idx >> 7) & 127;
        int d = idx & 127;
        dst[((size_t)n * T_ENC + t) * 128 + d] = f2bf(src[idx]);
    }
}

// E (t,n,d) bf16 hi/lo from emb[text], padding_idx=0
__global__ void prep_emb(const int* __restrict__ text, const float* __restrict__ emb,
                         u16* __restrict__ Ehi, u16* __restrict__ Elo) {
    size_t total = (size_t)LDEC * NB * HDIM;
    for (size_t idx = (size_t)blockIdx.x * 256 + threadIdx.x; idx < total;
         idx += (size_t)gridDim.x * 256) {
        int t = idx >> 16;            // 128*512 = 65536
        int n = (idx >> 9) & 127;
        int d = idx & 511;
        int tok = text[n * LDEC + t];
        float v = tok ? emb[(size_t)tok * HDIM + d] : 0.f;
        u16 hi = f2bf(v);
        Ehi[idx] = hi;
        Elo[idx] = f2bf(v - bfhi2f((unsigned int)hi));
    }
}

__global__ void prep_w1(const float* __restrict__ Wih, const float* __restrict__ Whh,
                        const float* __restrict__ bi, const float* __restrict__ bh,
                        u16* __restrict__ Whi, u16* __restrict__ Wlo,
                        float* __restrict__ bsum) {
    size_t total = (size_t)N1 * K1;
    for (size_t idx = (size_t)blockIdx.x * 256 + threadIdx.x; idx < total;
         idx += (size_t)gridDim.x * 256) {
        int c = idx / K1, k = idx % K1;
        float w = (k < 640) ? Wih[(size_t)c * 640 + k] : Whh[(size_t)c * 512 + (k - 640)];
        u16 hi = f2bf(w);
        Whi[idx] = hi;
        Wlo[idx] = f2bf(w - bfhi2f((unsigned int)hi));
    }
    int i = blockIdx.x * 256 + threadIdx.x;
    if (i < N1) bsum[i] = bi[i] + bh[i];
}

__global__ void prep_w2(const float* __restrict__ Wih, const float* __restrict__ Whh,
                        const float* __restrict__ bi, const float* __restrict__ bh,
                        u16* __restrict__ Whi, u16* __restrict__ Wlo,
                        float* __restrict__ bsum) {
    size_t total = (size_t)N2 * K2;
    for (size_t idx = (size_t)blockIdx.x * 256 + threadIdx.x; idx < total;
         idx += (size_t)gridDim.x * 256) {
        int c = idx / K2, k = idx % K2;
        float w = (k < 512) ? Wih[(size_t)c * 512 + k] : Whh[(size_t)c * 128 + (k - 512)];
        u16 hi = f2bf(w);
        Whi[idx] = hi;
        Wlo[idx] = f2bf(w - bfhi2f((unsigned int)hi));
    }
    int i = blockIdx.x * 256 + threadIdx.x;
    if (i < N2) bsum[i] = bi[i] + bh[i];
}

__global__ void init_state(float* c1, u16* h1hi, u16* h1lo,
                           float* c2, u16* h2hi, u16* h2lo,
                           u16* cxhi, u16* cxlo, const float* __restrict__ values) {
    int i = blockIdx.x * 256 + threadIdx.x;   // grid 256 -> 65536 threads
    c1[i] = 0.f; h1hi[i] = 0; h1lo[i] = 0;
    if (i < NB * KDIM) {
        c2[i] = 0.f; h2hi[i] = 0; h2lo[i] = 0;
        float v = values[i];                  // values[0] slice (N,V)
        u16 hi = f2bf(v);
        cxhi[i] = hi; cxlo[i] = f2bf(v - bfhi2f((unsigned int)hi));
    }
}

// ---------------- per-step kernels ----------------

// grid (4 n-tiles, 32 j-tiles), block 256 = 4 waves, wave = K-quarter (in-block k-split)
// wave tile: 32 n x (16 j x 4 gates), K-slice 288; LDS reduce; fused activation.
__global__ __launch_bounds__(256) void lstm1_fused(
    const u16* __restrict__ Ehi, const u16* __restrict__ Elo,
    const u16* __restrict__ cxhi, const u16* __restrict__ cxlo,
    const u16* __restrict__ h1hi_in, const u16* __restrict__ h1lo_in,
    const u16* __restrict__ W1hi, const u16* __restrict__ W1lo,
    const float* __restrict__ bsum,
    float* __restrict__ c1, u16* __restrict__ h1hi_o, u16* __restrict__ h1lo_o,
    int t)
{
    __shared__ float red[4][32][64];   // 32 KB
    int tid = threadIdx.x, lane = tid & 63, wk = tid >> 6;
    int l15 = lane & 15, l4 = lane >> 4;
    int n0 = blockIdx.x * 32;
    int j0 = blockIdx.y * 16;          // j in [0,512)
    int kbeg = wk * 288, kend = kbeg + 288;

    f32x4 zero = {0.f, 0.f, 0.f, 0.f};
    f32x4 acc[2][4];
#pragma unroll
    for (int m = 0; m < 2; ++m)
#pragma unroll
        for (int g = 0; g < 4; ++g) acc[m][g] = zero;

    size_t brow[4];
#pragma unroll
    for (int g = 0; g < 4; ++g) brow[g] = (size_t)(g * 512 + j0 + l15) * K1;
    int row0 = n0 + l15, row1 = n0 + 16 + l15;
    const u16* Et_hi = Ehi + (size_t)t * (NB * HDIM);
    const u16* Et_lo = Elo + (size_t)t * (NB * HDIM);

    for (int kk = kbeg; kk < kend; kk += 32) {
        int kb = kk + l4 * 8;
        const u16 *pah, *pal; size_t ao0, ao1;
        if (kk < 512) {
            pah = Et_hi; pal = Et_lo;
            ao0 = (size_t)row0 * 512 + kb; ao1 = (size_t)row1 * 512 + kb;
        } else if (kk < 640) {
            pah = cxhi; pal = cxlo;
            ao0 = (size_t)row0 * 128 + (kb - 512); ao1 = (size_t)row1 * 128 + (kb - 512);
        } else {
            pah = h1hi_in; pal = h1lo_in;
            ao0 = (size_t)row0 * 512 + (kb - 640); ao1 = (size_t)row1 * 512 + (kb - 640);
        }
        bf16x8 a0h = *(const bf16x8*)(pah + ao0);
        bf16x8 a0l = *(const bf16x8*)(pal + ao0);
        bf16x8 a1h = *(const bf16x8*)(pah + ao1);
        bf16x8 a1l = *(const bf16x8*)(pal + ao1);
#pragma unroll
        for (int g = 0; g < 4; ++g) {
            bf16x8 bh = *(const bf16x8*)(W1hi + brow[g] + kb);
            bf16x8 bl = *(const bf16x8*)(W1lo + brow[g] + kb);
            acc[0][g] = mfma16(a0h, bh, acc[0][g]);
            acc[0][g] = mfma16(a0h, bl, acc[0][g]);
            acc[0][g] = mfma16(a0l, bh, acc[0][g]);
            acc[1][g] = mfma16(a1h, bh, acc[1][g]);
            acc[1][g] = mfma16(a1h, bl, acc[1][g]);
            acc[1][g] = mfma16(a1l, bh, acc[1][g]);
        }
    }
#pragma unroll
    for (int mi = 0; mi < 2; ++mi)
#pragma unroll
        for (int g = 0; g < 4; ++g)
#pragma unroll
            for (int r = 0; r < 4; ++r)
                red[wk][mi * 16 + l4 * 4 + r][g * 16 + l15] = acc[mi][g][r];
    __syncthreads();

    for (int cell = tid; cell < 512; cell += 256) {
        int nl = cell >> 4, jl = cell & 15;
        float g[4];
#pragma unroll
        for (int gi = 0; gi < 4; ++gi) {
            float s = bsum[gi * 512 + j0 + jl];
#pragma unroll
            for (int w = 0; w < 4; ++w) s += red[w][nl][gi * 16 + jl];
            g[gi] = s;
        }
        int idx = (n0 + nl) * HDIM + j0 + jl;
        float cc = c1[idx];
        float i_ = 1.f / (1.f + expf(-g[0]));
        float f_ = 1.f / (1.f + expf(-g[1]));
        float g_ = tanhf(g[2]);
        float o_ = 1.f / (1.f + expf(-g[3]));
        float cn = f_ * cc + i_ * g_;
        c1[idx] = cn;
        float h = o_ * tanhf(cn);
        u16 hi = f2bf(h);
        h1hi_o[idx] = hi;
        h1lo_o[idx] = f2bf(h - bfhi2f((unsigned int)hi));
    }
}

// grid (4 n-tiles, 8 j-tiles), block 256 = 4 waves (in-block k-split of 640 -> 160)
__global__ __launch_bounds__(256) void lstm2_fused(
    const u16* __restrict__ h1hi, const u16* __restrict__ h1lo,
    const u16* __restrict__ h2hi_in, const u16* __restrict__ h2lo_in,
    const u16* __restrict__ W2hi, const u16* __restrict__ W2lo,
    const float* __restrict__ bsum,
    float* __restrict__ c2, float* __restrict__ h2f,
    u16* __restrict__ h2hi_o, u16* __restrict__ h2lo_o)
{
    __shared__ float red[4][32][64];
    int tid = threadIdx.x, lane = tid & 63, wk = tid >> 6;
    int l15 = lane & 15, l4 = lane >> 4;
    int n0 = blockIdx.x * 32;
    int j0 = blockIdx.y * 16;          // j in [0,128)
    int kbeg = wk * 160, kend = kbeg + 160;

    f32x4 zero = {0.f, 0.f, 0.f, 0.f};
    f32x4 acc[2][4];
#pragma unroll
    for (int m = 0; m < 2; ++m)
#pragma unroll
        for (int g = 0; g < 4; ++g) acc[m][g] = zero;

    size_t brow[4];
#pragma unroll
    for (int g = 0; g < 4; ++g) brow[g] = (size_t)(g * 128 + j0 + l15) * K2;
    int row0 = n0 + l15, row1 = n0 + 16 + l15;

    for (int kk = kbeg; kk < kend; kk += 32) {
        int kb = kk + l4 * 8;
        const u16 *pah, *pal; size_t ao0, ao1;
        if (kk < 512) {
            pah = h1hi; pal = h1lo;
            ao0 = (size_t)row0 * 512 + kb; ao1 = (size_t)row1 * 512 + kb;
        } else {
            pah = h2hi_in; pal = h2lo_in;
            ao0 = (size_t)row0 * 128 + (kb - 512); ao1 = (size_t)row1 * 128 + (kb - 512);
        }
        bf16x8 a0h = *(const bf16x8*)(pah + ao0);
        bf16x8 a0l = *(const bf16x8*)(pal + ao0);
        bf16x8 a1h = *(const bf16x8*)(pah + ao1);
        bf16x8 a1l = *(const bf16x8*)(pal + ao1);
#pragma unroll
        for (int g = 0; g < 4; ++g) {
            bf16x8 bh = *(const bf16x8*)(W2hi + brow[g] + kb);
            bf16x8 bl = *(const bf16x8*)(W2lo + brow[g] + kb);
            acc[0][g] = mfma16(a0h, bh, acc[0][g]);
            acc[0][g] = mfma16(a0h, bl, acc[0][g]);
            acc[0][g] = mfma16(a0l, bh, acc[0][g]);
            acc[1][g] = mfma16(a1h, bh, acc[1][g]);
            acc[1][g] = mfma16(a1h, bl, acc[1][g]);
            acc[1][g] = mfma16(a1l, bh, acc[1][g]);
        }
    }
#pragma unroll
    for (int mi = 0; mi < 2; ++mi)
#pragma unroll
        for (int g = 0; g < 4; ++g)
#pragma unroll
            for (int r = 0; r < 4; ++r)
                red[wk][mi * 16 + l4 * 4 + r][g * 16 + l15] = acc[mi][g][r];
    __syncthreads();

    for (int cell = tid; cell < 512; cell += 256) {
        int nl = cell >> 4, jl = cell & 15;
        float g[4];
#pragma unroll
        for (int gi = 0; gi < 4; ++gi) {
            float s = bsum[gi * 128 + j0 + jl];
#pragma unroll
            for (int w = 0; w < 4; ++w) s += red[w][nl][gi * 16 + jl];
            g[gi] = s;
        }
        int idx = (n0 + nl) * KDIM + j0 + jl;
        float cc = c2[idx];
        float i_ = 1.f / (1.f + expf(-g[0]));
        float f_ = 1.f / (1.f + expf(-g[1]));
        float g_ = tanhf(g[2]);
        float o_ = 1.f / (1.f + expf(-g[3]));
        float cn = f_ * cc + i_ * g_;
        c2[idx] = cn;
        float h = o_ * tanhf(cn);
        h2f[idx] = h;
        u16 hi = f2bf(h);
        h2hi_o[idx] = hi;
        h2lo_o[idx] = f2bf(h - bfhi2f((unsigned int)hi));
    }
}

// grid (NB, NC), block 256 (4 waves). kbf/vbf are (n, t, 128) bf16.
// Early-exit for fully-masked chunks: skip all K/V traffic.
__global__ __launch_bounds__(256) void attn_partial(
    const u16* __restrict__ kbf, const u16* __restrict__ vbf,
    const float* __restrict__ h2f, const int* __restrict__ lens,
    float* __restrict__ pmax, float* __restrict__ psum, float* __restrict__ pctx)
{
    int n = blockIdx.x, c = blockIdx.y, t0 = c * TC;
    int tid = threadIdx.x, lane = tid & 63, w = tid >> 6;
    int l15 = lane & 15, l4 = lane >> 4;
    int len = lens[n];
    if (t0 >= len) {                    // fully masked: exp(pmax-m)=0 in combine
        if (tid == 0) { pmax[n * NC + c] = -1e30f; psum[n * NC + c] = 0.f; }
        return;
    }
    __shared__ float pls[TC];
    __shared__ float red[8];
    __shared__ float cpart[4][VDIM];

    float h2r[8];
    {
        const float* hp = h2f + n * 128 + l15 * 8;
#pragma unroll
        for (int j = 0; j < 8; ++j) h2r[j] = hp[j];
    }

    const u16* kb_ = kbf + (size_t)n * T_ENC * 128;
    for (int q = w; q < 25; q += 4) {
        int tl = 4 * q + l4;
        int t = t0 + tl;
        uint4 u = *(const uint4*)(kb_ + (size_t)t * 128 + l15 * 8);
        float s = 0.f;
        s = fmaf(bfhi2f(u.x & 0xffffu), h2r[0], s);
        s = fmaf(bfhi2f(u.x >> 16),     h2r[1], s);
        s = fmaf(bfhi2f(u.y & 0xffffu), h2r[2], s);
        s = fmaf(bfhi2f(u.y >> 16),     h2r[3], s);
        s = fmaf(bfhi2f(u.z & 0xffffu), h2r[4], s);
        s = fmaf(bfhi2f(u.z >> 16),     h2r[5], s);
        s = fmaf(bfhi2f(u.w & 0xffffu), h2r[6], s);
        s = fmaf(bfhi2f(u.w >> 16),     h2r[7], s);
        s += __shfl_xor(s, 1, 64);
        s += __shfl_xor(s, 2, 64);
        s += __shfl_xor(s, 4, 64);
        s += __shfl_xor(s, 8, 64);
        if (t >= len) s = -1e30f;
        if (l15 == 0) pls[tl] = s;
    }
    __syncthreads();

    float m = -1e30f;
    for (int i = tid; i < TC; i += 256) m = fmaxf(m, pls[i]);
    for (int k = 32; k >= 1; k >>= 1) m = fmaxf(m, __shfl_xor(m, k, 64));
    if (lane == 0) red[w] = m;
    __syncthreads();
    m = fmaxf(fmaxf(red[0], red[1]), fmaxf(red[2], red[3]));

    float ssum = 0.f;
    for (int i = tid; i < TC; i += 256) {
        float pv = expf(pls[i] - m);
        pls[i] = pv;
        ssum += pv;
    }
    __syncthreads();
    for (int k = 32; k >= 1; k >>= 1) ssum += __shfl_xor(ssum, k, 64);
    if (lane == 0) red[4 + w] = ssum;
    __syncthreads();
    if (tid == 0) {
        pmax[n * NC + c] = m;
        psum[n * NC + c] = red[4] + red[5] + red[6] + red[7];
    }

    const u16* vb_ = vbf + (size_t)n * T_ENC * 128;
    int l5 = lane >> 5, l31 = lane & 31;
    float a4[4] = {0.f, 0.f, 0.f, 0.f};
    for (int p = w; p < 50; p += 4) {
        int tl = 2 * p + l5;
        int t = t0 + tl;
        float pv = pls[tl];
        uint2 u = *(const uint2*)(vb_ + (size_t)t * 128 + l31 * 4);
        a4[0] = fmaf(pv, bfhi2f(u.x & 0xffffu), a4[0]);
        a4[1] = fmaf(pv, bfhi2f(u.x >> 16),     a4[1]);
        a4[2] = fmaf(pv, bfhi2f(u.y & 0xffffu), a4[2]);
        a4[3] = fmaf(pv, bfhi2f(u.y >> 16),     a4[3]);
    }
#pragma unroll
    for (int j = 0; j < 4; ++j) a4[j] += __shfl_xor(a4[j], 32, 64);
    if (lane < 32) {
#pragma unroll
        for (int j = 0; j < 4; ++j) cpart[w][l31 * 4 + j] = a4[j];
    }
    __syncthreads();
    if (tid < 128)
        pctx[((size_t)n * NC + c) * VDIM + tid] =
            cpart[0][tid] + cpart[1][tid] + cpart[2][tid] + cpart[3][tid];
}

// grid NB, block 64
__global__ __launch_bounds__(64) void combine_pred(
    const float* __restrict__ pmax, const float* __restrict__ psum,
    const float* __restrict__ pctx, const float* __restrict__ h2f,
    u16* __restrict__ cxhi, u16* __restrict__ cxlo,
    const float* __restrict__ W_mos, const float* __restrict__ b_mos,
    float* __restrict__ out, int t)
{
    int n = blockIdx.x;
    int lane = threadIdx.x;

    float m = (lane < NC) ? pmax[n * NC + lane] : -1e30f;
    for (int k = 32; k >= 1; k >>= 1) m = fmaxf(m, __shfl_xor(m, k, 64));
    float s = (lane < NC) ? psum[n * NC + lane] * expf(pmax[n * NC + lane] - m) : 0.f;
    for (int k = 32; k >= 1; k >>= 1) s += __shfl_xor(s, k, 64);
    float inv = 1.f / s;

    __shared__ float xcat[2 * KDIM];
#pragma unroll
    for (int v2 = 0; v2 < 2; ++v2) {
        int v = lane + v2 * 64;
        float acc = 0.f;
        for (int c = 0; c < NC; ++c) {
            float e = expf(pmax[n * NC + c] - m);
            acc += pctx[((size_t)n * NC + c) * VDIM + v] * e;
        }
        acc *= inv;
        u16 hi = f2bf(acc);
        cxhi[n * 128 + v] = hi;
        cxlo[n * 128 + v] = f2bf(acc - bfhi2f((unsigned int)hi));
        xcat[KDIM + v] = acc;
    }
    xcat[lane] = h2f[n * 128 + lane];
    xcat[64 + lane] = h2f[n * 128 + 64 + lane];
    __syncthreads();

    float acc = b_mos[lane];
    const float* wr = W_mos + lane * (2 * KDIM);
#pragma unroll 4
    for (int i = 0; i < 2 * KDIM; ++i) acc += xcat[i] * wr[i];
    out[((size_t)n * LDEC + t) * ADIM + lane] = acc;
}

// ---------------- launcher ----------------

extern "C" void kernel_launch(void* const* d_in, const int* in_sizes, int n_in,
                              void* d_out, int out_size, void* d_ws, size_t ws_size,
                              hipStream_t stream)
{
    const float* key    = (const float*)d_in[0];
    const float* values = (const float*)d_in[1];
    const int*   lens   = (const int*)d_in[2];
    const int*   text   = (const int*)d_in[3];
    const float* emb    = (const float*)d_in[4];
    const float* W_ih1  = (const float*)d_in[5];
    const float* W_hh1  = (const float*)d_in[6];
    const float* b_ih1  = (const float*)d_in[7];
    const float* b_hh1  = (const float*)d_in[8];
    const float* W_ih2  = (const float*)d_in[9];
    const float* W_hh2  = (const float*)d_in[10];
    const float* b_ih2  = (const float*)d_in[11];
    const float* b_hh2  = (const float*)d_in[12];
    const float* W_mos  = (const float*)d_in[13];
    const float* b_mos  = (const float*)d_in[14];
    float* out = (float*)d_out;

    char* base = (char*)d_ws;
    size_t off = 0;
    auto alloc = [&](size_t bytes) -> char* {
        char* r = base + off;
        off += (bytes + 255) & ~(size_t)255;
        return r;
    };
    u16* kbf  = (u16*)alloc((size_t)T_ENC * NB * 128 * 2);
    u16* vbf  = (u16*)alloc((size_t)T_ENC * NB * 128 * 2);
    u16* Ehi  = (u16*)alloc((size_t)LDEC * NB * HDIM * 2);
    u16* Elo  = (u16*)alloc((size_t)LDEC * NB * HDIM * 2);
    u16* W1hi = (u16*)alloc((size_t)N1 * K1 * 2);
    u16* W1lo = (u16*)alloc((size_t)N1 * K1 * 2);
    u16* W2hi = (u16*)alloc((size_t)N2 * K2 * 2);
    u16* W2lo = (u16*)alloc((size_t)N2 * K2 * 2);
    float* bsum1 = (float*)alloc(N1 * 4);
    float* bsum2 = (float*)alloc(N2 * 4);
    u16* h1hiA = (u16*)alloc(NB * HDIM * 2);
    u16* h1loA = (u16*)alloc(NB * HDIM * 2);
    u16* h1hiB = (u16*)alloc(NB * HDIM * 2);
    u16* h1loB = (u16*)alloc(NB * HDIM * 2);
    u16* h2hiA = (u16*)alloc(NB * KDIM * 2);
    u16* h2loA = (u16*)alloc(NB * KDIM * 2);
    u16* h2hiB = (u16*)alloc(NB * KDIM * 2);
    u16* h2loB = (u16*)alloc(NB * KDIM * 2);
    float* c1  = (float*)alloc(NB * HDIM * 4);
    float* c2  = (float*)alloc(NB * KDIM * 4);
    float* h2f = (float*)alloc(NB * KDIM * 4);
    u16* cxhi = (u16*)alloc(NB * VDIM * 2);
    u16* cxlo = (u16*)alloc(NB * VDIM * 2);
    float* pmax = (float*)alloc(NB * NC * 4);
    float* psum = (float*)alloc(NB * NC * 4);
    float* pctx = (float*)alloc((size_t)NB * NC * VDIM * 4);
    (void)ws_size; (void)in_sizes; (void)n_in; (void)out_size;

    cvt_tr<<<4096, 256, 0, stream>>>(key, kbf);
    cvt_tr<<<4096, 256, 0, stream>>>(values, vbf);
    prep_emb<<<4096, 256, 0, stream>>>(text, emb, Ehi, Elo);
    prep_w1<<<2048, 256, 0, stream>>>(W_ih1, W_hh1, b_ih1, b_hh1, W1hi, W1lo, bsum1);
    prep_w2<<<512, 256, 0, stream>>>(W_ih2, W_hh2, b_ih2, b_hh2, W2hi, W2lo, bsum2);
    init_state<<<256, 256, 0, stream>>>(c1, h1hiA, h1loA, c2, h2hiA, h2loA,
                                        cxhi, cxlo, values);

    for (int t = 0; t < LDEC; ++t) {
        u16* h1hi_i = (t & 1) ? h1hiB : h1hiA;
        u16* h1lo_i = (t & 1) ? h1loB : h1loA;
        u16* h1hi_o = (t & 1) ? h1hiA : h1hiB;
        u16* h1lo_o = (t & 1) ? h1loA : h1loB;
        u16* h2hi_i = (t & 1) ? h2hiB : h2hiA;
        u16* h2lo_i = (t & 1) ? h2loB : h2loA;
        u16* h2hi_o = (t & 1) ? h2hiA : h2hiB;
        u16* h2lo_o = (t & 1) ? h2loA : h2loB;

        lstm1_fused<<<dim3(4, 32), 256, 0, stream>>>(
            Ehi, Elo, cxhi, cxlo, h1hi_i, h1lo_i, W1hi, W1lo, bsum1,
            c1, h1hi_o, h1lo_o, t);
        lstm2_fused<<<dim3(4, 8), 256, 0, stream>>>(
            h1hi_o, h1lo_o, h2hi_i, h2lo_i, W2hi, W2lo, bsum2,
            c2, h2f, h2hi_o, h2lo_o);
        attn_partial<<<dim3(NB, NC), 256, 0, stream>>>(kbf, vbf, h2f, lens,
                                                       pmax, psum, pctx);
        combine_pred<<<NB, 64, 0, stream>>>(pmax, psum, pctx, h2f,
                                            cxhi, cxlo, W_mos, b_mos, out, t);
    }
}